// Round 9
// baseline (110.547 us; speedup 1.0000x reference)
//
#include <hip/hip_runtime.h>
#include <stdint.h>

#define BN 4096
#define DK 512
#define THRESH 0.5f
#define MARGIN 0.1f

typedef __attribute__((ext_vector_type(4))) float f32x4;
typedef __attribute__((ext_vector_type(8))) unsigned short ushort8;

__device__ __forceinline__ unsigned short f2bf(float f) {
    unsigned u = __float_as_uint(f);
    u += 0x7FFFu + ((u >> 16) & 1u);   // RNE
    return (unsigned short)(u >> 16);
}
__device__ __forceinline__ float bf2f(unsigned short b) {
    return __uint_as_float((unsigned)b << 16);
}

// fp32 -> OCP e4m3fn, RNE (software; inputs here are |x| <~ 0.5 so the
// clamp/NaN paths are never hot). Subnormal: m = round(a * 2^9).
__device__ __forceinline__ unsigned char f2fp8(float x) {
    float a = fabsf(x);
    unsigned s = (__float_as_uint(x) >> 24) & 0x80u;
    if (a >= 448.f) return (unsigned char)(s | 0x7E);      // clamp to max finite
    if (a < 0.015625f) {                                    // < 2^-6: subnormal
        int m = (int)(a * 512.0f + 0.5f);                   // 0..8 (8 == 2^-6 normal)
        return (unsigned char)(s | m);
    }
    unsigned u = __float_as_uint(a);
    u += 0x0FFFFFu + ((u >> 20) & 1u);                      // RNE into 3-bit mantissa
    unsigned e = (u >> 23) - 127u + 7u;
    unsigned m = (u >> 20) & 7u;
    if (e >= 16u) return (unsigned char)(s | 0x7E);
    return (unsigned char)(s | (e << 3) | m);
}

__device__ __forceinline__ void async_cp16(void* lds, const void* g) {
    __builtin_amdgcn_global_load_lds(
        (const __attribute__((address_space(1))) void*)g,
        (__attribute__((address_space(3))) void*)lds,
        16, 0, 0);
}

// feats fp32 -> fp8 e4m3 (for MFMA); block 0 thread 0 zero-inits out[0]
// (harness re-poisons d_out to 0xAA before every timed replay).
__global__ void cvt_kernel(const float4* __restrict__ in, uchar4* __restrict__ out,
                           float* __restrict__ loss_out) {
    int i = blockIdx.x * blockDim.x + threadIdx.x;   // 524288 threads, 4 elems each
    float4 v = in[i];
    uchar4 o;
    o.x = f2fp8(v.x); o.y = f2fp8(v.y); o.z = f2fp8(v.z); o.w = f2fp8(v.w);
    out[i] = o;
    if (blockIdx.x == 0 && threadIdx.x == 0) loss_out[0] = 0.f;
}

// Triangular GEMM, fp8 inputs: sim = F8 @ F8^T (fp32 accumulate), bf16 store.
// Only the 528 upper-triangle 128x128 tiles; off-diagonal blocks mirror-store
// C^T via an LDS round-trip. Diagonal tiles skip B staging (A==B).
//
// DOUBLE-BUFFERED single-barrier K-loop (BK=128 B fp8): prefetch for slab s+1
// is issued AFTER the barrier that publishes slab s, so the entire MFMA phase
// of slab s (~1000 cyc) runs while those loads are in flight; the next
// iteration's barrier drains loads that are already complete. This removes
// the exposed load latency of the issue-then-barrier structure (the m97
// plateau). 64 KB LDS -> 2 blocks/CU, which matches the natural occupancy of
// 528 blocks on 256 CUs, so no occupancy loss. Buffer safety with ONE barrier
// per iter: prefetch(s+1) writes buf[(s+1)&1], whose previous readers
// (compute s-1) all passed the iteration-top barrier.
// Staging swizzle: 16B chunk index XORed with (r&7) on the GLOBAL gather side
// (preserving global_load_lds's lane-contiguous LDS dest).
__global__ __launch_bounds__(256, 2) void ms_gemm(
    const unsigned char* __restrict__ Fb,   // fp8 e4m3 [4096][512] row-major
    unsigned short* __restrict__ simb)      // bf16 bits [4096][4096]
{
    __shared__ __align__(16) unsigned char SMEMB[65536];  // 2 x (16K As | 16K Bs)
    unsigned short* SMEM = (unsigned short*)SMEMB;        // 128x128 bf16 mirror reuse

    const int t    = threadIdx.x;
    const int lane = t & 63;
    const int w    = t >> 6;
    const int wr   = w >> 1, wc = w & 1;
    const int quad = lane >> 4;
    const int cIdx = lane & 15;

    // map linear block id -> upper-triangle tile (by <= bx), 528 blocks
    int l = blockIdx.x, by = 0;
    while (l >= 32 - by) { l -= (32 - by); ++by; }
    const int bx = by + l;
    const int rowBase = by * 128;
    const int colBase = bx * 128;
    const bool diag = (by == bx);

    f32x4 acc[4][4];
#pragma unroll
    for (int i = 0; i < 4; ++i)
#pragma unroll
        for (int j = 0; j < 4; ++j) acc[i][j] = (f32x4){0.f, 0.f, 0.f, 0.f};

    // staging addresses (swizzled) for this thread: 4 A-chunks + 4 B-chunks
    const int id0 = t;                 // chunk ids t, t+256, t+512, t+768
    // prefetch slab 0 into buffer 0
#pragma unroll
    for (int it = 0; it < 4; ++it) {
        const int id = it * 256 + id0;
        const int r  = id >> 3;
        const int gc = (id & 7) ^ (r & 7);
        async_cp16(SMEMB + id * 16,
                   Fb + (size_t)(rowBase + r) * DK + 0 + gc * 16);
    }
    if (!diag) {
#pragma unroll
        for (int it = 0; it < 4; ++it) {
            const int id = it * 256 + id0;
            const int r  = id >> 3;
            const int gc = (id & 7) ^ (r & 7);
            async_cp16(SMEMB + 16384 + id * 16,
                       Fb + (size_t)(colBase + r) * DK + 0 + gc * 16);
        }
    }

#pragma unroll
    for (int s = 0; s < 4; ++s) {
        __syncthreads();   // publishes slab s (drains loads issued last iter,
                           // which had the whole previous MFMA phase in flight)

        if (s < 3) {       // prefetch slab s+1 into the other buffer
            const int k1 = (s + 1) * 128;
            unsigned char* dstA = SMEMB + ((s + 1) & 1) * 32768;
#pragma unroll
            for (int it = 0; it < 4; ++it) {
                const int id = it * 256 + id0;
                const int r  = id >> 3;
                const int gc = (id & 7) ^ (r & 7);
                async_cp16(dstA + id * 16,
                           Fb + (size_t)(rowBase + r) * DK + k1 + gc * 16);
            }
            if (!diag) {
#pragma unroll
                for (int it = 0; it < 4; ++it) {
                    const int id = it * 256 + id0;
                    const int r  = id >> 3;
                    const int gc = (id & 7) ^ (r & 7);
                    async_cp16(dstA + 16384 + id * 16,
                               Fb + (size_t)(colBase + r) * DK + k1 + gc * 16);
                }
            }
        }

        const unsigned char* As   = SMEMB + (s & 1) * 32768;
        const unsigned char* Bsel = diag ? As : (As + 16384);

#pragma unroll
        for (int kk = 0; kk < 4; ++kk) {
            long af[4], bg[4];
#pragma unroll
            for (int im = 0; im < 4; ++im) {
                int r = wr * 64 + im * 16 + cIdx;         // A[m=lane&15][k=quad*8+j]
                int u = kk * 4 + quad;                    // 8B k-unit 0..15
                int p = (u >> 1) ^ (r & 7);               // de-swizzled 16B chunk
                af[im] = *reinterpret_cast<const long*>(
                    &As[r * 128 + p * 16 + (u & 1) * 8]);
            }
#pragma unroll
            for (int jn = 0; jn < 4; ++jn) {
                int c = wc * 64 + jn * 16 + cIdx;         // B[k=quad*8+j][n=lane&15]
                int u = kk * 4 + quad;
                int p = (u >> 1) ^ (c & 7);
                bg[jn] = *reinterpret_cast<const long*>(
                    &Bsel[c * 128 + p * 16 + (u & 1) * 8]);
            }
#pragma unroll
            for (int im = 0; im < 4; ++im)
#pragma unroll
                for (int jn = 0; jn < 4; ++jn)
                    acc[im][jn] = __builtin_amdgcn_mfma_f32_16x16x32_fp8_fp8(
                        af[im], bg[jn], acc[im][jn], 0, 0, 0);
        }
    }

    // Direct store. C/D layout (16x16): col=lane&15, row=quad*4+reg.
#pragma unroll
    for (int im = 0; im < 4; ++im)
#pragma unroll
        for (int rg = 0; rg < 4; ++rg) {
            const int grow = rowBase + wr * 64 + im * 16 + quad * 4 + rg;
            unsigned short* dst = simb + (size_t)grow * BN + colBase + wc * 64 + cIdx;
#pragma unroll
            for (int jn = 0; jn < 4; ++jn)
                dst[jn * 16] = f2bf(acc[im][jn][rg]);
        }

    if (diag) return;

    __syncthreads();   // all LDS reads of the K-loop done before SMEM reuse

    // Mirror store: write C^T into SMEM (phys 16B-chunk XOR-swizzled by column),
    // then read rows of C^T and store 16B-coalesced to sim[col][row].
#pragma unroll
    for (int im = 0; im < 4; ++im)
#pragma unroll
        for (int jn = 0; jn < 4; ++jn) {
            ushort4 v;
            v.x = f2bf(acc[im][jn][0]);
            v.y = f2bf(acc[im][jn][1]);
            v.z = f2bf(acc[im][jn][2]);
            v.w = f2bf(acc[im][jn][3]);
            const int c  = wc * 64 + jn * 16 + cIdx;       // tile col
            const int r  = wr * 64 + im * 16 + quad * 4;   // tile row (rg=0)
            const int r8 = r >> 3;                         // 16B-chunk index 0..15
            const int ri = r & 7;                          // 0 or 4 within chunk
            *reinterpret_cast<ushort4*>(
                &SMEM[c * 128 + ((r8 ^ (c & 15)) << 3) + ri]) = v;
        }
    __syncthreads();

    const int lch = t & 7;    // low 16B chunk of the transposed row
    const int trw = t >> 3;   // 0..31
#pragma unroll
    for (int it = 0; it < 4; ++it) {
        const int tr = it * 32 + trw;                      // transposed row = orig col
        const int q1 = lch ^ (tr & 15);
        const int q2 = (lch + 8) ^ (tr & 15);
        ushort8 a = *reinterpret_cast<const ushort8*>(&SMEM[tr * 128 + q1 * 8]);
        ushort8 b = *reinterpret_cast<const ushort8*>(&SMEM[tr * 128 + q2 * 8]);
        unsigned short* dst = simb + (size_t)(colBase + tr) * BN + rowBase;
        *reinterpret_cast<ushort8*>(&dst[lch * 8])       = a;
        *reinterpret_cast<ushort8*>(&dst[(lch + 8) * 8]) = b;
    }
}

// Per-row pass: one wave owns one full row (held in 32 VGPRs), so the row's
// min/max thresholds are wave-local. 1024 blocks x 4 waves x 1 row.
// Labels staged transposed in LDS (conflict-free per-(j,e) reads); exp bodies
// wave-ballot-guarded with an exact any() kept for validity (neg cutoff
// s <= 0.125 drops only terms < e^-15; Dloss <= 3.1e-5).
__global__ __launch_bounds__(256) void ms_rows(
    const unsigned short* __restrict__ simb,
    const int* __restrict__ labels,
    const int* __restrict__ label_num,
    float* __restrict__ out)
{
    __shared__ int   labT[8][512];   // 16 KB, labT[i&7][i>>3] = labels[i]
    __shared__ float bsum[4];

    const int t    = threadIdx.x;
    const int lane = t & 63;
    const int w    = t >> 6;

    for (int i = t; i < BN; i += 256) labT[i & 7][i >> 3] = labels[i];
    __syncthreads();

    const int lim = BN - label_num[0];
    const int row = blockIdx.x * 4 + w;
    const int lr  = labT[row & 7][row >> 3];
    const ushort8* rp = (const ushort8*)(simb + (size_t)row * BN);

    ushort8 d[8];
    uint64_t mpos = 0, msame = 0;
    float mn = INFINITY, mx = -INFINITY;
#pragma unroll
    for (int j = 0; j < 8; ++j) {
        d[j] = rp[j * 64 + lane];
        const int c8 = j * 64 + lane;            // col>>3 for this lane's 8 elems
#pragma unroll
        for (int e = 0; e < 8; ++e) {
            const int col = c8 * 8 + e;
            const float s = bf2f(d[j][e]);
            const bool same = (labT[e][c8] == lr);   // conflict-free LDS read
            const bool pos  = same && (col != row);
            if (pos)   mn = fminf(mn, s);
            if (!same) mx = fmaxf(mx, s);
            msame |= (uint64_t)same << (j * 8 + e);
            mpos  |= (uint64_t)pos  << (j * 8 + e);
        }
    }
#pragma unroll
    for (int off = 1; off < 64; off <<= 1) {
        mn = fminf(mn, __shfl_xor(mn, off, 64));
        mx = fmaxf(mx, __shfl_xor(mx, off, 64));
    }
    const float tP = (mn < 1e30f)  ? mn : 0.2f;   // pos_thr fallback
    const float tN = (mx > -1e30f) ? mx : 0.8f;   // neg_thr fallback

    float ps = 0.f, ns = 0.f;
    bool anyN = false;
#pragma unroll
    for (int j = 0; j < 8; ++j)
#pragma unroll
        for (int e = 0; e < 8; ++e) {
            const int k = j * 8 + e;
            const float s = bf2f(d[j][e]);
            const bool doP = ((mpos >> k) & 1) && (s - MARGIN < tN);
            if (__any(doP))
                ps += doP ? __expf(-2.0f * (s - THRESH)) : 0.f;
            const bool doN = !((msame >> k) & 1) && (s + MARGIN > tP);
            anyN |= doN;                       // exact any() for validity
            const bool doNe = doN && (s > 0.125f);   // numeric cutoff
            if (__any(doNe))
                ns += doNe ? __expf(40.0f * (s - THRESH)) : 0.f;
        }
#pragma unroll
    for (int off = 1; off < 64; off <<= 1) {
        ps += __shfl_xor(ps, off, 64);
        ns += __shfl_xor(ns, off, 64);
    }
    const bool anyNw = __any(anyN);
    // all pos terms kept -> ps>0 <=> any mined pos; neg validity via anyNw
    float wsum = 0.f;
    if (lane == 0 && ps > 0.f && anyNw && row < lim)
        wsum = 0.5f * log1pf(ps) + 0.025f * log1pf(ns);

    if (lane == 0) bsum[w] = wsum;
    __syncthreads();
    if (t == 0)
        atomicAdd(out, (bsum[0] + bsum[1] + bsum[2] + bsum[3]) * (1.0f / (float)BN));
}

extern "C" void kernel_launch(void* const* d_in, const int* in_sizes, int n_in,
                              void* d_out, int out_size, void* d_ws, size_t ws_size,
                              hipStream_t stream)
{
    const float* feats     = (const float*)d_in[0];
    const int*   labels    = (const int*)d_in[1];
    const int*   label_num = (const int*)d_in[2];
    float*       out       = (float*)d_out;

    char* ws = (char*)d_ws;
    unsigned char*  Fb   = (unsigned char*)ws;                         // 2 MB fp8 feats
    unsigned short* simb = (unsigned short*)(ws + 4u * 1024u * 1024u); // 32 MB bf16 sim

    cvt_kernel<<<2048, 256, 0, stream>>>((const float4*)feats, (uchar4*)Fb, out);

    ms_gemm<<<528, 256, 0, stream>>>(Fb, simb);   // upper-triangle tiles only

    ms_rows<<<1024, 256, 0, stream>>>(simb, labels, label_num, out);
}

// Round 10
// 110.236 us; speedup vs baseline: 1.0028x; 1.0028x over previous
//
#include <hip/hip_runtime.h>
#include <stdint.h>

#define BN 4096
#define DK 512
#define THRESH 0.5f
#define MARGIN 0.1f

typedef __attribute__((ext_vector_type(4))) float f32x4;
typedef __attribute__((ext_vector_type(8))) unsigned short ushort8;

__device__ __forceinline__ unsigned short f2bf(float f) {
    unsigned u = __float_as_uint(f);
    u += 0x7FFFu + ((u >> 16) & 1u);   // RNE
    return (unsigned short)(u >> 16);
}
__device__ __forceinline__ float bf2f(unsigned short b) {
    return __uint_as_float((unsigned)b << 16);
}

// fp32 -> OCP e4m3fn, RNE (software; inputs here are |x| <~ 0.5 so the
// clamp/NaN paths are never hot). Subnormal: m = round(a * 2^9).
__device__ __forceinline__ unsigned char f2fp8(float x) {
    float a = fabsf(x);
    unsigned s = (__float_as_uint(x) >> 24) & 0x80u;
    if (a >= 448.f) return (unsigned char)(s | 0x7E);      // clamp to max finite
    if (a < 0.015625f) {                                    // < 2^-6: subnormal
        int m = (int)(a * 512.0f + 0.5f);                   // 0..8 (8 == 2^-6 normal)
        return (unsigned char)(s | m);
    }
    unsigned u = __float_as_uint(a);
    u += 0x0FFFFFu + ((u >> 20) & 1u);                      // RNE into 3-bit mantissa
    unsigned e = (u >> 23) - 127u + 7u;
    unsigned m = (u >> 20) & 7u;
    if (e >= 16u) return (unsigned char)(s | 0x7E);
    return (unsigned char)(s | (e << 3) | m);
}

__device__ __forceinline__ void async_cp16(void* lds, const void* g) {
    __builtin_amdgcn_global_load_lds(
        (const __attribute__((address_space(1))) void*)g,
        (__attribute__((address_space(3))) void*)lds,
        16, 0, 0);
}

// feats fp32 -> fp8 e4m3 (for MFMA); block 0 thread 0 zero-inits out[0]
// (harness re-poisons d_out to 0xAA before every timed replay).
__global__ void cvt_kernel(const float4* __restrict__ in, uchar4* __restrict__ out,
                           float* __restrict__ loss_out) {
    int i = blockIdx.x * blockDim.x + threadIdx.x;   // 524288 threads, 4 elems each
    float4 v = in[i];
    uchar4 o;
    o.x = f2fp8(v.x); o.y = f2fp8(v.y); o.z = f2fp8(v.z); o.w = f2fp8(v.w);
    out[i] = o;
    if (blockIdx.x == 0 && threadIdx.x == 0) loss_out[0] = 0.f;
}

// Triangular GEMM, fp8 inputs: sim = F8 @ F8^T (fp32 accumulate), bf16 store.
// Only the 528 upper-triangle 128x128 tiles are computed; off-diagonal blocks
// mirror-store C^T via an LDS round-trip. Diagonal tiles skip B staging (A==B).
//
// ROUND-8 CONFIG (session best): single-buffered BK=128 (16 KB/matrix, 32 KB
// LDS total, 4 blocks/CU). Round-9's explicit double-buffer (64 KB LDS,
// 2 blocks/CU) was neutral-to-negative — matching the guide's m99/m100
// finding that implicit wave-level overlap at higher occupancy already
// captures the pipelining gain. Do not re-attempt dbuf on this structure.
// Staging swizzle: 16B chunk index XORed with (r&7) on the GLOBAL gather side
// (preserving global_load_lds's lane-contiguous LDS dest).
__global__ __launch_bounds__(256, 4) void ms_gemm(
    const unsigned char* __restrict__ Fb,   // fp8 e4m3 [4096][512] row-major
    unsigned short* __restrict__ simb)      // bf16 bits [4096][4096]
{
    __shared__ __align__(16) unsigned char SMEMB[32768];  // 16K As | 16K Bs
    unsigned char* As = SMEMB;
    unsigned char* Bs = SMEMB + 16384;
    unsigned short* SMEM = (unsigned short*)SMEMB;        // 128x128 bf16 mirror reuse

    const int t    = threadIdx.x;
    const int lane = t & 63;
    const int w    = t >> 6;
    const int wr   = w >> 1, wc = w & 1;
    const int quad = lane >> 4;
    const int cIdx = lane & 15;

    // map linear block id -> upper-triangle tile (by <= bx), 528 blocks
    int l = blockIdx.x, by = 0;
    while (l >= 32 - by) { l -= (32 - by); ++by; }
    const int bx = by + l;
    const int rowBase = by * 128;
    const int colBase = bx * 128;
    const bool diag = (by == bx);
    const unsigned char* Bsel = diag ? As : Bs;   // diagonal: A==B, skip B staging

    f32x4 acc[4][4];
#pragma unroll
    for (int i = 0; i < 4; ++i)
#pragma unroll
        for (int j = 0; j < 4; ++j) acc[i][j] = (f32x4){0.f, 0.f, 0.f, 0.f};

    for (int k0 = 0; k0 < DK; k0 += 128) {   // 4 iterations (BK=128 bytes)
#pragma unroll
        for (int it = 0; it < 4; ++it) {
            const int id = it * 256 + t;          // 0..1023
            const int r  = id >> 3;               // staging row 0..127
            const int gc = (id & 7) ^ (r & 7);    // XOR-swizzled 16B chunk
            async_cp16(As + id * 16,
                       Fb + (size_t)(rowBase + r) * DK + k0 + gc * 16);
        }
        if (!diag) {
#pragma unroll
            for (int it = 0; it < 4; ++it) {
                const int id = it * 256 + t;
                const int r  = id >> 3;
                const int gc = (id & 7) ^ (r & 7);
                async_cp16(Bs + id * 16,
                           Fb + (size_t)(colBase + r) * DK + k0 + gc * 16);
            }
        }
        __syncthreads();   // compiler drains vmcnt before s_barrier

#pragma unroll
        for (int kk = 0; kk < 4; ++kk) {
            long af[4], bg[4];
#pragma unroll
            for (int im = 0; im < 4; ++im) {
                int r = wr * 64 + im * 16 + cIdx;         // A[m=lane&15][k=quad*8+j]
                int u = kk * 4 + quad;                    // 8B k-unit 0..15
                int p = (u >> 1) ^ (r & 7);               // de-swizzled 16B chunk
                af[im] = *reinterpret_cast<const long*>(
                    &As[r * 128 + p * 16 + (u & 1) * 8]);
            }
#pragma unroll
            for (int jn = 0; jn < 4; ++jn) {
                int c = wc * 64 + jn * 16 + cIdx;         // B[k=quad*8+j][n=lane&15]
                int u = kk * 4 + quad;
                int p = (u >> 1) ^ (c & 7);
                bg[jn] = *reinterpret_cast<const long*>(
                    &Bsel[c * 128 + p * 16 + (u & 1) * 8]);
            }
#pragma unroll
            for (int im = 0; im < 4; ++im)
#pragma unroll
                for (int jn = 0; jn < 4; ++jn)
                    acc[im][jn] = __builtin_amdgcn_mfma_f32_16x16x32_fp8_fp8(
                        af[im], bg[jn], acc[im][jn], 0, 0, 0);
        }
        __syncthreads();   // last iteration: also guards SMEM reuse below
    }

    // Direct store. C/D layout (16x16): col=lane&15, row=quad*4+reg.
#pragma unroll
    for (int im = 0; im < 4; ++im)
#pragma unroll
        for (int rg = 0; rg < 4; ++rg) {
            const int grow = rowBase + wr * 64 + im * 16 + quad * 4 + rg;
            unsigned short* dst = simb + (size_t)grow * BN + colBase + wc * 64 + cIdx;
#pragma unroll
            for (int jn = 0; jn < 4; ++jn)
                dst[jn * 16] = f2bf(acc[im][jn][rg]);
        }

    if (diag) return;

    // Mirror store: write C^T into SMEM (phys 16B-chunk XOR-swizzled by column),
    // then read rows of C^T and store 16B-coalesced to sim[col][row].
#pragma unroll
    for (int im = 0; im < 4; ++im)
#pragma unroll
        for (int jn = 0; jn < 4; ++jn) {
            ushort4 v;
            v.x = f2bf(acc[im][jn][0]);
            v.y = f2bf(acc[im][jn][1]);
            v.z = f2bf(acc[im][jn][2]);
            v.w = f2bf(acc[im][jn][3]);
            const int c  = wc * 64 + jn * 16 + cIdx;       // tile col
            const int r  = wr * 64 + im * 16 + quad * 4;   // tile row (rg=0)
            const int r8 = r >> 3;                         // 16B-chunk index 0..15
            const int ri = r & 7;                          // 0 or 4 within chunk
            *reinterpret_cast<ushort4*>(
                &SMEM[c * 128 + ((r8 ^ (c & 15)) << 3) + ri]) = v;
        }
    __syncthreads();

    const int lch = t & 7;    // low 16B chunk of the transposed row
    const int trw = t >> 3;   // 0..31
#pragma unroll
    for (int it = 0; it < 4; ++it) {
        const int tr = it * 32 + trw;                      // transposed row = orig col
        const int q1 = lch ^ (tr & 15);
        const int q2 = (lch + 8) ^ (tr & 15);
        ushort8 a = *reinterpret_cast<const ushort8*>(&SMEM[tr * 128 + q1 * 8]);
        ushort8 b = *reinterpret_cast<const ushort8*>(&SMEM[tr * 128 + q2 * 8]);
        unsigned short* dst = simb + (size_t)(colBase + tr) * BN + rowBase;
        *reinterpret_cast<ushort8*>(&dst[lch * 8])       = a;
        *reinterpret_cast<ushort8*>(&dst[(lch + 8) * 8]) = b;
    }
}

// Per-row pass: one wave owns one full row (held in 32 VGPRs), so the row's
// min/max thresholds are wave-local. 1024 blocks x 4 waves x 1 row.
// Labels staged transposed in LDS (conflict-free per-(j,e) reads); exp bodies
// wave-ballot-guarded with an exact any() kept for validity (neg cutoff
// s <= 0.125 drops only terms < e^-15; Dloss <= 3.1e-5).
// NOTE: the ~60 us ms_rows rows in round-9's rocprof capture were a
// serialized/cold-cache replay artifact (FETCH 16.6 MB @ 267 GB/s); in the
// timed run sim is L3-resident from ms_gemm's stores and this kernel is ~6 us.
__global__ __launch_bounds__(256) void ms_rows(
    const unsigned short* __restrict__ simb,
    const int* __restrict__ labels,
    const int* __restrict__ label_num,
    float* __restrict__ out)
{
    __shared__ int   labT[8][512];   // 16 KB, labT[i&7][i>>3] = labels[i]
    __shared__ float bsum[4];

    const int t    = threadIdx.x;
    const int lane = t & 63;
    const int w    = t >> 6;

    for (int i = t; i < BN; i += 256) labT[i & 7][i >> 3] = labels[i];
    __syncthreads();

    const int lim = BN - label_num[0];
    const int row = blockIdx.x * 4 + w;
    const int lr  = labT[row & 7][row >> 3];
    const ushort8* rp = (const ushort8*)(simb + (size_t)row * BN);

    ushort8 d[8];
    uint64_t mpos = 0, msame = 0;
    float mn = INFINITY, mx = -INFINITY;
#pragma unroll
    for (int j = 0; j < 8; ++j) {
        d[j] = rp[j * 64 + lane];
        const int c8 = j * 64 + lane;            // col>>3 for this lane's 8 elems
#pragma unroll
        for (int e = 0; e < 8; ++e) {
            const int col = c8 * 8 + e;
            const float s = bf2f(d[j][e]);
            const bool same = (labT[e][c8] == lr);   // conflict-free LDS read
            const bool pos  = same && (col != row);
            if (pos)   mn = fminf(mn, s);
            if (!same) mx = fmaxf(mx, s);
            msame |= (uint64_t)same << (j * 8 + e);
            mpos  |= (uint64_t)pos  << (j * 8 + e);
        }
    }
#pragma unroll
    for (int off = 1; off < 64; off <<= 1) {
        mn = fminf(mn, __shfl_xor(mn, off, 64));
        mx = fmaxf(mx, __shfl_xor(mx, off, 64));
    }
    const float tP = (mn < 1e30f)  ? mn : 0.2f;   // pos_thr fallback
    const float tN = (mx > -1e30f) ? mx : 0.8f;   // neg_thr fallback

    float ps = 0.f, ns = 0.f;
    bool anyN = false;
#pragma unroll
    for (int j = 0; j < 8; ++j)
#pragma unroll
        for (int e = 0; e < 8; ++e) {
            const int k = j * 8 + e;
            const float s = bf2f(d[j][e]);
            const bool doP = ((mpos >> k) & 1) && (s - MARGIN < tN);
            if (__any(doP))
                ps += doP ? __expf(-2.0f * (s - THRESH)) : 0.f;
            const bool doN = !((msame >> k) & 1) && (s + MARGIN > tP);
            anyN |= doN;                       // exact any() for validity
            const bool doNe = doN && (s > 0.125f);   // numeric cutoff
            if (__any(doNe))
                ns += doNe ? __expf(40.0f * (s - THRESH)) : 0.f;
        }
#pragma unroll
    for (int off = 1; off < 64; off <<= 1) {
        ps += __shfl_xor(ps, off, 64);
        ns += __shfl_xor(ns, off, 64);
    }
    const bool anyNw = __any(anyN);
    // all pos terms kept -> ps>0 <=> any mined pos; neg validity via anyNw
    float wsum = 0.f;
    if (lane == 0 && ps > 0.f && anyNw && row < lim)
        wsum = 0.5f * log1pf(ps) + 0.025f * log1pf(ns);

    if (lane == 0) bsum[w] = wsum;
    __syncthreads();
    if (t == 0)
        atomicAdd(out, (bsum[0] + bsum[1] + bsum[2] + bsum[3]) * (1.0f / (float)BN));
}

extern "C" void kernel_launch(void* const* d_in, const int* in_sizes, int n_in,
                              void* d_out, int out_size, void* d_ws, size_t ws_size,
                              hipStream_t stream)
{
    const float* feats     = (const float*)d_in[0];
    const int*   labels    = (const int*)d_in[1];
    const int*   label_num = (const int*)d_in[2];
    float*       out       = (float*)d_out;

    char* ws = (char*)d_ws;
    unsigned char*  Fb   = (unsigned char*)ws;                         // 2 MB fp8 feats
    unsigned short* simb = (unsigned short*)(ws + 4u * 1024u * 1024u); // 32 MB bf16 sim

    cvt_kernel<<<2048, 256, 0, stream>>>((const float4*)feats, (uchar4*)Fb, out);

    ms_gemm<<<528, 256, 0, stream>>>(Fb, simb);   // upper-triangle tiles only

    ms_rows<<<1024, 256, 0, stream>>>(simb, labels, label_num, out);
}